// Round 8
// baseline (196.975 us; speedup 1.0000x reference)
//
#include <hip/hip_runtime.h>
#include <hip/hip_bf16.h>
#include <cstdint>

typedef unsigned short u16;
typedef unsigned short u16x4 __attribute__((ext_vector_type(4)));
typedef unsigned short u16x8 __attribute__((ext_vector_type(8)));
typedef _Float16 f16x8 __attribute__((ext_vector_type(8)));
typedef float f32x4 __attribute__((ext_vector_type(4)));

constexpr int NN   = 8192;
constexpr int INC  = 128;
constexpr int HIDC = 256;
constexpr int OUTC = 128;
constexpr int KSPLIT = 8;

__device__ __forceinline__ u16 f2h(float f) {
    _Float16 h = (_Float16)f;
    return __builtin_bit_cast(u16, h);
}
__device__ __forceinline__ float h2f(u16 u) {
    return (float)__builtin_bit_cast(_Float16, u);
}
__device__ __forceinline__ float fast_sigmoid(float z) {
    float e;
    asm("v_exp_f32 %0, %1" : "=v"(e) : "v"(z * -1.44269504088896f));
    float s;
    asm("v_rcp_f32 %0, %1" : "=v"(s) : "v"(1.0f + e));
    return s;
}

typedef __attribute__((address_space(1))) const void* gptr_t;
typedef __attribute__((address_space(3))) void* sptr_t;
#define GLD16(g, s) __builtin_amdgcn_global_load_lds((gptr_t)(g), (sptr_t)(s), 16, 0, 0)

// ---------------------------------------------------------------------------
// k_adj v9 (R6-identical): race-free psum, diag tiles last, block 0 = W2T.
// ---------------------------------------------------------------------------
__global__ __launch_bounds__(512, 4) void k_adj(const float* __restrict__ P,
                                                u16* __restrict__ AH,
                                                float* __restrict__ psum,
                                                const float* __restrict__ W2,
                                                u16* __restrict__ W2T) {
    const int t = threadIdx.x;
    if (blockIdx.x == 0) {
        for (int e = t; e < OUTC * HIDC; e += 512) {
            int c = e >> 8, k = e & 255;
            W2T[c * HIDC + k] = f2h(W2[k * OUTC + c]);
        }
        return;
    }
    int bid = blockIdx.x - 1;                 // 0..2079
    int bi, bj;
    if (bid >= 2016)      { bi = bj = bid - 2016; }          // 64 diag tiles, last
    else if (bid >= 1984) { bi = 31; bj = 32 + (bid - 1984); }
    else {
        int u = bid >> 6, v = bid & 63;       // u 0..30
        if (v < 63 - u) { bi = u;      bj = u + 1 + v; }
        else            { bi = 62 - u; bj = v; }
    }
    constexpr int LW = 136;                   // row stride in halves
    __shared__ u16 hB[128 * LW];
    __shared__ float cs[8][128];
    const int i0 = bi * 128, j0 = bj * 128;
    const bool diag = (bi == bj);

    // ---- stage transposed tile -> fp16 LDS
    #pragma unroll
    for (int p = 0; p < 4; ++p) {
        int idx = p * 512 + t;                // 128 rows x 16 blocks
        int r = idx >> 4, m = idx & 15;
        const float* pb = P + (size_t)(j0 + r) * NN + i0 + m * 8;
        f32x4 b0 = __builtin_nontemporal_load((const f32x4*)pb);
        f32x4 b1 = __builtin_nontemporal_load((const f32x4*)(pb + 4));
        u16x8 hb;
        hb[0] = f2h(b0[0]); hb[1] = f2h(b0[1]); hb[2] = f2h(b0[2]); hb[3] = f2h(b0[3]);
        hb[4] = f2h(b1[0]); hb[5] = f2h(b1[1]); hb[6] = f2h(b1[2]); hb[7] = f2h(b1[3]);
        int pos = m ^ ((r >> 3) & 7);
        *(u16x8*)&hB[r * LW + pos * 8] = hb;
    }

    // ---- A-patch direct from global, fp32 (pre-barrier: hides under wait)
    const int rb = t >> 4, cb = t & 15;
    const int R = rb * 4, C = cb * 8;
    f32x4 a0[4], a1[4];
    #pragma unroll
    for (int i = 0; i < 4; ++i) {
        const float* pa = P + (size_t)(i0 + R + i) * NN + j0 + C;
        a0[i] = __builtin_nontemporal_load((const f32x4*)pa);
        a1[i] = __builtin_nontemporal_load((const f32x4*)(pa + 4));
    }
    __syncthreads();

    float rsum[4] = {0.f, 0.f, 0.f, 0.f};
    float csum[8] = {0.f, 0.f, 0.f, 0.f, 0.f, 0.f, 0.f, 0.f};
    u16x4 mir[8];
    {
        u16x4 bv[8];
        #pragma unroll
        for (int j = 0; j < 8; ++j) {
            int r = C + j;
            int pos = (rb >> 1) ^ (cb & 7);
            bv[j] = *(const u16x4*)&hB[r * LW + pos * 8 + (rb & 1) * 4];
        }
        #pragma unroll
        for (int i = 0; i < 4; ++i) {
            u16x8 o;
            #pragma unroll
            for (int j = 0; j < 8; ++j) {
                float av = (j < 4) ? a0[i][j] : a1[i][j - 4];
                float z = 0.5f * (av + h2f(bv[j][i]));
                bool dg = (i0 + R + i) == (j0 + C + j);
                if (dg) z += 1.0f;
                float s = fast_sigmoid(z);
                if (dg) s += 1.0f;
                u16 h = f2h(s);
                o[j] = h;
                mir[j][i] = h;
                rsum[i] += s;
                csum[j] += s;
            }
            *(u16x8*)(AH + (size_t)(i0 + R + i) * NN + j0 + C) = o;
        }
        if (!diag) {
            #pragma unroll
            for (int j = 0; j < 8; ++j) {
                int r = C + j;
                int pos = (rb >> 1) ^ (cb & 7);
                *(u16x4*)&hB[r * LW + pos * 8 + (rb & 1) * 4] = mir[j];
            }
        }
    }

    #pragma unroll
    for (int m = 1; m <= 8; m <<= 1) {
        #pragma unroll
        for (int i = 0; i < 4; ++i) rsum[i] += __shfl_xor(rsum[i], m);
    }
    if (cb == 0) {
        f32x4 rv = {rsum[0], rsum[1], rsum[2], rsum[3]};
        *(f32x4*)&psum[(size_t)bj * NN + i0 + R] = rv;
    }

    if (!diag) {
        #pragma unroll
        for (int j = 0; j < 8; ++j) {
            csum[j] += __shfl_xor(csum[j], 16);
            csum[j] += __shfl_xor(csum[j], 32);
        }
        const int w = t >> 6;
        if ((t & 48) == 0) {
            #pragma unroll
            for (int j = 0; j < 8; ++j) cs[w][C + j] = csum[j];
        }
    }
    __syncthreads();

    if (!diag) {
        const int r2 = t >> 4, m = t & 15;
        #pragma unroll
        for (int p = 0; p < 4; ++p) {
            int rr = r2 + p * 32;
            int pos = m ^ ((rr >> 3) & 7);
            *(u16x8*)(AH + (size_t)(j0 + rr) * NN + i0 + m * 8) =
                *(const u16x8*)&hB[rr * LW + pos * 8];
        }
        if (t < 128) {
            float s = 0.f;
            #pragma unroll
            for (int k = 0; k < 8; ++k) s += cs[k][t];
            psum[(size_t)bi * NN + j0 + t] = s;   // unique writer
        }
    }
}

// ---------------------------------------------------------------------------
// k_xw1 (R6-identical): psum reduce -> rowsum, then scaled x@W1 -> XW1T.
// ---------------------------------------------------------------------------
__global__ __launch_bounds__(256) void k_xw1(const float* __restrict__ x,
                                             const float* __restrict__ W1,
                                             const float* __restrict__ psum,
                                             float* __restrict__ rowsum,
                                             u16* __restrict__ XW1T) {
    const int t = threadIdx.x;
    __shared__ float xs[32 * 129];
    __shared__ float rs_s[32];
    const int i0 = blockIdx.x * 32;
    if (t < 32) {
        float rs = 0.f;
        #pragma unroll 8
        for (int v = 0; v < 64; ++v) rs += psum[(size_t)v * NN + i0 + t];
        rs_s[t] = rs;
        rowsum[i0 + t] = rs;                  // publish for epi1/epi2
    }
    #pragma unroll
    for (int p = 0; p < 4; ++p) {
        int idx = p * 256 + t;
        int r = idx >> 5, c4 = idx & 31;
        f32x4 v = __builtin_nontemporal_load(
            (const f32x4*)(x + (size_t)(i0 + r) * INC + c4 * 4));
        int o = r * 129 + c4 * 4;
        xs[o] = v[0]; xs[o + 1] = v[1]; xs[o + 2] = v[2]; xs[o + 3] = v[3];
    }
    __syncthreads();
    const int i = t & 31, g = t >> 5;
    const float di = 1.0f / sqrtf(rs_s[i]);
    #pragma unroll
    for (int p = 0; p < 2; ++p) {
        const int cbase = g * 32 + p * 16;
        float acc[16];
        #pragma unroll
        for (int cc = 0; cc < 16; ++cc) acc[cc] = 0.f;
        for (int k = 0; k < 128; ++k) {
            float xv = xs[i * 129 + k];
            const float4* wr4 = reinterpret_cast<const float4*>(W1 + k * HIDC + cbase);
            float4 w0 = wr4[0], w1 = wr4[1], w2 = wr4[2], w3 = wr4[3];
            acc[0]  = fmaf(xv, w0.x, acc[0]);  acc[1]  = fmaf(xv, w0.y, acc[1]);
            acc[2]  = fmaf(xv, w0.z, acc[2]);  acc[3]  = fmaf(xv, w0.w, acc[3]);
            acc[4]  = fmaf(xv, w1.x, acc[4]);  acc[5]  = fmaf(xv, w1.y, acc[5]);
            acc[6]  = fmaf(xv, w1.z, acc[6]);  acc[7]  = fmaf(xv, w1.w, acc[7]);
            acc[8]  = fmaf(xv, w2.x, acc[8]);  acc[9]  = fmaf(xv, w2.y, acc[9]);
            acc[10] = fmaf(xv, w2.z, acc[10]); acc[11] = fmaf(xv, w2.w, acc[11]);
            acc[12] = fmaf(xv, w3.x, acc[12]); acc[13] = fmaf(xv, w3.y, acc[13]);
            acc[14] = fmaf(xv, w3.z, acc[14]); acc[15] = fmaf(xv, w3.w, acc[15]);
        }
        #pragma unroll
        for (int cc = 0; cc < 16; ++cc)
            XW1T[(size_t)(cbase + cc) * NN + i0 + i] = f2h(di * acc[cc]);
    }
}

// ---------------------------------------------------------------------------
// 8-phase MFMA GEMM, BM=256, BK=64, 8 waves. K-loop R6-identical.
// C-write fragment-native (R7) + NONTEMPORAL: partial is single-use scratch,
// keep it out of L2/L3 so AH (128MB) stays Infinity-Cache-resident across
// both GEMMs' A-sweeps.
// ---------------------------------------------------------------------------
#define PH_MID() do { __builtin_amdgcn_s_barrier();                             \
    asm volatile("s_waitcnt lgkmcnt(0)" ::: "memory");                          \
    __builtin_amdgcn_sched_barrier(0);                                          \
    __builtin_amdgcn_s_setprio(1); } while (0)

#define PH_NW() do { __builtin_amdgcn_s_setprio(0);                             \
    __builtin_amdgcn_s_barrier(); } while (0)

#define PH_W() do { __builtin_amdgcn_s_setprio(0);                              \
    if constexpr (BN == 256) { asm volatile("s_waitcnt vmcnt(6)" ::: "memory"); } \
    else                     { asm volatile("s_waitcnt vmcnt(4)" ::: "memory"); } \
    __builtin_amdgcn_s_barrier(); } while (0)

#define PH_W0() do { __builtin_amdgcn_s_setprio(0);                             \
    asm volatile("s_waitcnt vmcnt(0)" ::: "memory");                            \
    __builtin_amdgcn_s_barrier(); } while (0)

template <int BN>
__global__ __launch_bounds__(512, 2) void k_gemm8(const u16* __restrict__ A,
                                                  const u16* __restrict__ BT,
                                                  u16* __restrict__ partial) {
    constexpr int NI = BN / 128;
    constexpr int NQB = BN / 64;
    constexpr int BUFB = BN * 128;
    constexpr int KCH = NN / KSPLIT;          // 1024
    constexpr int NT = KCH / 64;              // 16
    constexpr int ITER = NT / 2;              // 8 (last peeled)
    __shared__ __align__(16) char lds[65536 + 2 * BUFB];

    const int t = threadIdx.x;
    const int l = t & 63, w = t >> 6;
    const int wr = w >> 2, wc = w & 3;
    const int g2 = (blockIdx.x & 7) * 32 + (blockIdx.x >> 3);
    const int m0 = (g2 & 31) * 256;
    const int kc = g2 >> 5;
    const int kbase = kc * KCH;

    const int D16 = t * 16;
    const int Ds = D16 ^ (((D16 >> 7) & 7) << 4);
    const int rS = Ds >> 7, cS = (Ds & 127) >> 1;

    f32x4 acc[8][NI * 2];
    #pragma unroll
    for (int i = 0; i < 8; ++i)
        #pragma unroll
        for (int j = 0; j < NI * 2; ++j) acc[i][j] = {0.f, 0.f, 0.f, 0.f};

    f16x8 a[4][2];
    f16x8 bf[2][NI][2];

    auto stageA = [&](int b, int q, int tile) {
        GLD16(A + (size_t)(m0 + q * 64 + rS) * NN + kbase + tile * 64 + cS,
              &lds[b * 32768 + q * 8192 + D16]);
    };
    auto stageB = [&](int b, int q, int tile) {
        GLD16(BT + (size_t)(q * 64 + rS) * NN + kbase + tile * 64 + cS,
              &lds[65536 + b * BUFB + q * 8192 + D16]);
    };
    auto readA = [&](int b, int mh) {
        #pragma unroll
        for (int mi = 0; mi < 4; ++mi)
            #pragma unroll
            for (int s = 0; s < 2; ++s) {
                int r = wr * 128 + mh * 64 + mi * 16 + (l & 15);
                a[mi][s] = *(const f16x8*)&lds[b * 32768 + r * 128 +
                    ((s * 64 + ((l >> 4) * 16)) ^ ((r & 7) << 4))];
            }
    };
    auto readB = [&](int b, int nh) {
        #pragma unroll
        for (int ni = 0; ni < NI; ++ni)
            #pragma unroll
            for (int s = 0; s < 2; ++s) {
                int r = wc * (BN / 4) + nh * (NI * 16) + ni * 16 + (l & 15);
                bf[nh][ni][s] = *(const f16x8*)&lds[65536 + b * BUFB + r * 128 +
                    ((s * 64 + ((l >> 4) * 16)) ^ ((r & 7) << 4))];
            }
    };
    auto mfmaq = [&](int mh, int nh) {
        #pragma unroll
        for (int s = 0; s < 2; ++s)
            #pragma unroll
            for (int mi = 0; mi < 4; ++mi)
                #pragma unroll
                for (int ni = 0; ni < NI; ++ni)
                    acc[mh * 4 + mi][nh * NI + ni] =
                        __builtin_amdgcn_mfma_f32_16x16x32_f16(a[mi][s], bf[nh][ni][s],
                            acc[mh * 4 + mi][nh * NI + ni], 0, 0, 0);
    };

    #pragma unroll
    for (int q = 0; q < NQB; ++q) stageB(0, q, 0);
    #pragma unroll
    for (int q = 0; q < 4; ++q) stageA(0, q, 0);
    #pragma unroll
    for (int q = 0; q < NQB; ++q) stageB(1, q, 1);
    stageA(1, 0, 1); stageA(1, 1, 1);
    if constexpr (BN == 256) { asm volatile("s_waitcnt vmcnt(6)" ::: "memory"); }
    else                     { asm volatile("s_waitcnt vmcnt(4)" ::: "memory"); }
    __builtin_amdgcn_s_barrier();

    for (int it = 0; it < ITER - 1; ++it) {
        const int TP = 2 * it + 1, TE = 2 * it + 2, TO = 2 * it + 3;
        readA(0, 0); readB(0, 0); stageA(1, 2, TP); stageA(1, 3, TP);
        PH_MID(); mfmaq(0, 0); PH_NW();
        readB(0, 1);
        PH_MID(); mfmaq(0, 1); PH_NW();
        readA(0, 1); stageB(0, 0, TE); stageB(0, 1, TE);
        PH_MID(); mfmaq(1, 0); PH_NW();
        if constexpr (BN == 256) { stageB(0, 2, TE); stageB(0, 3, TE); }
        stageA(0, 0, TE); stageA(0, 1, TE);
        PH_MID(); mfmaq(1, 1); PH_W();
        readA(1, 0); readB(1, 0); stageA(0, 2, TE); stageA(0, 3, TE);
        PH_MID(); mfmaq(0, 0); PH_NW();
        readB(1, 1);
        PH_MID(); mfmaq(0, 1); PH_NW();
        readA(1, 1); stageB(1, 0, TO); stageB(1, 1, TO);
        PH_MID(); mfmaq(1, 0); PH_NW();
        if constexpr (BN == 256) { stageB(1, 2, TO); stageB(1, 3, TO); }
        stageA(1, 0, TO); stageA(1, 1, TO);
        PH_MID(); mfmaq(1, 1); PH_W();
    }
    readA(0, 0); readB(0, 0); stageA(1, 2, NT - 1); stageA(1, 3, NT - 1);
    PH_MID(); mfmaq(0, 0); PH_NW();
    readB(0, 1);
    PH_MID(); mfmaq(0, 1); PH_NW();
    readA(0, 1);
    PH_MID(); mfmaq(1, 0); PH_NW();
    PH_MID(); mfmaq(1, 1); PH_W0();
    readA(1, 0); readB(1, 0);
    PH_MID(); mfmaq(0, 0); PH_NW();
    readB(1, 1);
    PH_MID(); mfmaq(0, 1); PH_NW();
    readA(1, 1);
    PH_MID(); mfmaq(1, 0); PH_NW();
    PH_MID(); mfmaq(1, 1);
    __builtin_amdgcn_s_setprio(0);

    // ---- fragment-native C-write: 8B/lane, 512B contiguous per fragment,
    // NONTEMPORAL (single-use scratch; preserve L3 for AH)
    u16* pout = partial + (size_t)kc * NN * BN + (size_t)(g2 & 31) * (256 * BN);
    #pragma unroll
    for (int mh = 0; mh < 2; ++mh)
        #pragma unroll
        for (int mi = 0; mi < 4; ++mi)
            #pragma unroll
            for (int nh = 0; nh < 2; ++nh)
                #pragma unroll
                for (int ni = 0; ni < NI; ++ni) {
                    int f = (((w * 2 + mh) * 4 + mi) * 2 + nh) * NI + ni;
                    u16x4 v;
                    #pragma unroll
                    for (int j = 0; j < 4; ++j)
                        v[j] = f2h(acc[mh * 4 + mi][nh * NI + ni][j]);
                    __builtin_nontemporal_store(v,
                        (u16x4*)(pout + ((size_t)f * 64 + l) * 4));
                }
}

// ---------------------------------------------------------------------------
// Fused epi1 + h@W2, fragment-native partial reads (R7-identical).
// ---------------------------------------------------------------------------
__global__ __launch_bounds__(512) void k_epi1hw2m(const u16* __restrict__ partial,
                                                  const float* __restrict__ rowsum,
                                                  const float* __restrict__ b1,
                                                  const u16* __restrict__ W2T,
                                                  u16* __restrict__ HW2T) {
    __shared__ __align__(16) char lds[81920];
    const int t = threadIdx.x;
    const int l = t & 63, w = t >> 6;
    const int i0 = blockIdx.x * 32;

    #pragma unroll
    for (int p = 0; p < 8; ++p) {
        int D = (p * 512 + t) * 16;
        int row = D >> 9;
        int col = (D & 511) ^ ((row & 7) << 4);
        GLD16(W2T + (size_t)row * HIDC + (col >> 1), &lds[D]);
    }

    // ---- decode fragment coords: rows i0+rq*4..+3, cols c..c+3
    {
        const int rq = w;                     // row-quad 0..7
        const int c = l * 4;                  // col 0..252
        const int cl = c & 15, ni = (c >> 4) & 1, nh = (c >> 5) & 1, wcq = c >> 6;
        const int lr0 = i0 & 255;
        const int wrq = lr0 >> 7, mhq = (lr0 >> 6) & 1;
        const int mi = ((lr0 >> 4) & 3) + (rq >> 2);
        const int lgrp = rq & 3;
        const int mb = i0 >> 8;
        const int f = ((((wrq * 4 + wcq) * 2 + mhq) * 4 + mi) * 2 + nh) * 2 + ni;
        const size_t boff = (size_t)mb * 65536 + ((size_t)f * 64 + lgrp * 16 + cl) * 4;
        float s[16];
        #pragma unroll
        for (int e = 0; e < 16; ++e) s[e] = 0.f;
        #pragma unroll
        for (int kc = 0; kc < KSPLIT; ++kc) {
            const u16* src = partial + (size_t)kc * NN * HIDC + boff;
            u16x8 p0 = __builtin_nontemporal_load((const u16x8*)src);
            u16x8 p1 = __builtin_nontemporal_load((const u16x8*)(src + 8));
            #pragma unroll
            for (int e = 0; e < 8; ++e) { s[e] += h2f(p0[e]); s[8 + e] += h2f(p1[e]); }
        }
        float di[4];
        #pragma unroll
        for (int j = 0; j < 4; ++j) di[j] = 1.0f / sqrtf(rowsum[i0 + rq * 4 + j]);
        f32x4 b1v = *(const f32x4*)(b1 + c);
        #pragma unroll
        for (int k = 0; k < 4; ++k)
            #pragma unroll
            for (int j = 0; j < 4; ++j) {
                float hv = di[j] * fmaxf(fmaf(di[j], s[k * 4 + j], b1v[k]), 0.f);
                int il = rq * 4 + j;
                *(u16*)&lds[65536 + il * 512 + ((2 * (c + k)) ^ ((il & 7) << 4))] = f2h(hv);
            }
    }
    asm volatile("s_waitcnt vmcnt(0)" ::: "memory");
    __syncthreads();

    const int wm = w >> 1, wn = w & 1;        // wm 0..3 (c-quad), wn 0..1 (i-half)
    f32x4 acc[2];
    acc[0] = {0.f, 0.f, 0.f, 0.f}; acc[1] = {0.f, 0.f, 0.f, 0.f};
    for (int kt = 0; kt < 8; ++kt) {
        f16x8 av[2], bv;
        const int cb2 = kt * 64 + (l >> 4) * 16;
        #pragma unroll
        for (int mi = 0; mi < 2; ++mi) {
            int r = wm * 32 + mi * 16 + (l & 15);
            av[mi] = *(const f16x8*)&lds[r * 512 + (cb2 ^ ((r & 7) << 4))];
        }
        {
            int ri = wn * 16 + (l & 15);
            bv = *(const f16x8*)&lds[65536 + ri * 512 + (cb2 ^ ((ri & 7) << 4))];
        }
        #pragma unroll
        for (int mi = 0; mi < 2; ++mi)
            acc[mi] = __builtin_amdgcn_mfma_f32_16x16x32_f16(av[mi], bv, acc[mi], 0, 0, 0);
    }
    #pragma unroll
    for (int mi = 0; mi < 2; ++mi)
        #pragma unroll
        for (int j = 0; j < 4; ++j) {
            int c = wm * 32 + mi * 16 + (l >> 4) * 4 + j;
            int ic = wn * 16 + (l & 15);
            HW2T[(size_t)c * NN + i0 + ic] = f2h(acc[mi][j]);
        }
}

// ---------------------------------------------------------------------------
// Final epilogue, fragment-native partial reads (R7-identical).
// ---------------------------------------------------------------------------
__global__ __launch_bounds__(256) void k_epi2(const u16* __restrict__ partial,
                                              const float* __restrict__ rowsum,
                                              const float* __restrict__ b2,
                                              float* __restrict__ out) {
    const int idx = blockIdx.x * 256 + threadIdx.x;   // 65536 = NN*OUTC/16
    const int rq = idx >> 5;              // row-quad 0..2047
    const int c4g = idx & 31;
    const int c = c4g * 4;
    const int cl = c & 15, nh = (c >> 4) & 1, wc = c >> 5;
    const int mb = rq >> 6;
    const int lr4 = rq & 63;              // row-quad within 256-row panel
    const int wr = lr4 >> 5, mh = (lr4 >> 4) & 1, mi = (lr4 >> 2) & 3, lgrp = lr4 & 3;
    const int f = (((wr * 4 + wc) * 2 + mh) * 4 + mi) * 2 + nh;
    const size_t boff = (size_t)mb * 32768 + ((size_t)f * 64 + lgrp * 16 + cl) * 4;
    float s[16];
    #pragma unroll
    for (int e = 0; e < 16; ++e) s[e] = 0.f;
    #pragma unroll
    for (int kc = 0; kc < KSPLIT; ++kc) {
        const u16* src = partial + (size_t)kc * NN * OUTC + boff;
        u16x8 p0 = __builtin_nontemporal_load((const u16x8*)src);
        u16x8 p1 = __builtin_nontemporal_load((const u16x8*)(src + 8));
        #pragma unroll
        for (int e = 0; e < 8; ++e) { s[e] += h2f(p0[e]); s[8 + e] += h2f(p1[e]); }
    }
    const int i_base = rq * 4;
    f32x4 b2v = *(const f32x4*)(b2 + c);
    #pragma unroll
    for (int j = 0; j < 4; ++j) {
        const float di = 1.0f / sqrtf(rowsum[i_base + j]);
        float4 o = make_float4(fmaf(di, s[0 * 4 + j], b2v[0]),
                               fmaf(di, s[1 * 4 + j], b2v[1]),
                               fmaf(di, s[2 * 4 + j], b2v[2]),
                               fmaf(di, s[3 * 4 + j], b2v[3]));
        *reinterpret_cast<float4*>(out + (size_t)(i_base + j) * OUTC + c) = o;
    }
}

// ---------------------------------------------------------------------------
extern "C" void kernel_launch(void* const* d_in, const int* in_sizes, int n_in,
                              void* d_out, int out_size, void* d_ws, size_t ws_size,
                              hipStream_t stream) {
    const float* x  = (const float*)d_in[0];
    const float* P  = (const float*)d_in[1];
    const float* W1 = (const float*)d_in[2];
    const float* b1 = (const float*)d_in[3];
    const float* W2 = (const float*)d_in[4];
    const float* b2 = (const float*)d_in[5];
    float* out = (float*)d_out;
    char* ws = (char*)d_ws;

    u16*   AH      = (u16*)(ws);                    // 134,217,728 B
    u16*   XW1T    = (u16*)(ws + 134217728ull);     // 4 MB
    u16*   W2T     = (u16*)(ws + 138412032ull);     // 64 KB
    u16*   HW2T    = (u16*)(ws + 138477568ull);     // 2 MB
    float* rowsum  = (float*)(ws + 140574720ull);   // 32 KB
    u16*   partial = (u16*)(ws + 140607488ull);     // 33.5 MB
    float* psum    = (float*)(ws + 174161920ull);   // 2 MB (64 x 8192 fp32)

    k_adj<<<2081, 512, 0, stream>>>(P, AH, psum, W2, W2T);
    k_xw1<<<256, 256, 0, stream>>>(x, W1, psum, rowsum, XW1T);
    k_gemm8<HIDC><<<256, 512, 0, stream>>>(AH, XW1T, partial);
    k_epi1hw2m<<<256, 512, 0, stream>>>(partial, rowsum, b1, W2T, HW2T);
    k_gemm8<OUTC><<<256, 512, 0, stream>>>(AH, HW2T, partial);
    k_epi2<<<256, 256, 0, stream>>>(partial, rowsum, b2, out);
}

// Round 9
// 194.988 us; speedup vs baseline: 1.0102x; 1.0102x over previous
//
#include <hip/hip_runtime.h>
#include <hip/hip_bf16.h>
#include <cstdint>

typedef unsigned short u16;
typedef unsigned short u16x4 __attribute__((ext_vector_type(4)));
typedef unsigned short u16x8 __attribute__((ext_vector_type(8)));
typedef _Float16 f16x8 __attribute__((ext_vector_type(8)));
typedef float f32x4 __attribute__((ext_vector_type(4)));

constexpr int NN   = 8192;
constexpr int INC  = 128;
constexpr int HIDC = 256;
constexpr int OUTC = 128;
constexpr int KSPLIT = 8;

__device__ __forceinline__ u16 f2h(float f) {
    _Float16 h = (_Float16)f;
    return __builtin_bit_cast(u16, h);
}
__device__ __forceinline__ float h2f(u16 u) {
    return (float)__builtin_bit_cast(_Float16, u);
}
__device__ __forceinline__ float fast_sigmoid(float z) {
    float e;
    asm("v_exp_f32 %0, %1" : "=v"(e) : "v"(z * -1.44269504088896f));
    float s;
    asm("v_rcp_f32 %0, %1" : "=v"(s) : "v"(1.0f + e));
    return s;
}

typedef __attribute__((address_space(1))) const void* gptr_t;
typedef __attribute__((address_space(3))) void* sptr_t;
#define GLD16(g, s) __builtin_amdgcn_global_load_lds((gptr_t)(g), (sptr_t)(s), 16, 0, 0)

// ---------------------------------------------------------------------------
// k_adj: race-free psum, diag tiles last, block 0 = W2T transpose.
// ---------------------------------------------------------------------------
__global__ __launch_bounds__(512, 4) void k_adj(const float* __restrict__ P,
                                                u16* __restrict__ AH,
                                                float* __restrict__ psum,
                                                const float* __restrict__ W2,
                                                u16* __restrict__ W2T) {
    const int t = threadIdx.x;
    if (blockIdx.x == 0) {
        for (int e = t; e < OUTC * HIDC; e += 512) {
            int c = e >> 8, k = e & 255;
            W2T[c * HIDC + k] = f2h(W2[k * OUTC + c]);
        }
        return;
    }
    int bid = blockIdx.x - 1;                 // 0..2079
    int bi, bj;
    if (bid >= 2016)      { bi = bj = bid - 2016; }          // 64 diag tiles, last
    else if (bid >= 1984) { bi = 31; bj = 32 + (bid - 1984); }
    else {
        int u = bid >> 6, v = bid & 63;       // u 0..30
        if (v < 63 - u) { bi = u;      bj = u + 1 + v; }
        else            { bi = 62 - u; bj = v; }
    }
    constexpr int LW = 136;                   // row stride in halves
    __shared__ u16 hB[128 * LW];
    __shared__ float cs[8][128];
    const int i0 = bi * 128, j0 = bj * 128;
    const bool diag = (bi == bj);

    // ---- stage transposed tile -> fp16 LDS
    #pragma unroll
    for (int p = 0; p < 4; ++p) {
        int idx = p * 512 + t;                // 128 rows x 16 blocks
        int r = idx >> 4, m = idx & 15;
        const float* pb = P + (size_t)(j0 + r) * NN + i0 + m * 8;
        f32x4 b0 = __builtin_nontemporal_load((const f32x4*)pb);
        f32x4 b1 = __builtin_nontemporal_load((const f32x4*)(pb + 4));
        u16x8 hb;
        hb[0] = f2h(b0[0]); hb[1] = f2h(b0[1]); hb[2] = f2h(b0[2]); hb[3] = f2h(b0[3]);
        hb[4] = f2h(b1[0]); hb[5] = f2h(b1[1]); hb[6] = f2h(b1[2]); hb[7] = f2h(b1[3]);
        int pos = m ^ ((r >> 3) & 7);
        *(u16x8*)&hB[r * LW + pos * 8] = hb;
    }

    // ---- A-patch direct from global, fp32 (pre-barrier: hides under wait)
    const int rb = t >> 4, cb = t & 15;
    const int R = rb * 4, C = cb * 8;
    f32x4 a0[4], a1[4];
    #pragma unroll
    for (int i = 0; i < 4; ++i) {
        const float* pa = P + (size_t)(i0 + R + i) * NN + j0 + C;
        a0[i] = __builtin_nontemporal_load((const f32x4*)pa);
        a1[i] = __builtin_nontemporal_load((const f32x4*)(pa + 4));
    }
    __syncthreads();

    float rsum[4] = {0.f, 0.f, 0.f, 0.f};
    float csum[8] = {0.f, 0.f, 0.f, 0.f, 0.f, 0.f, 0.f, 0.f};
    u16x4 mir[8];
    {
        u16x4 bv[8];
        #pragma unroll
        for (int j = 0; j < 8; ++j) {
            int r = C + j;
            int pos = (rb >> 1) ^ (cb & 7);
            bv[j] = *(const u16x4*)&hB[r * LW + pos * 8 + (rb & 1) * 4];
        }
        #pragma unroll
        for (int i = 0; i < 4; ++i) {
            u16x8 o;
            #pragma unroll
            for (int j = 0; j < 8; ++j) {
                float av = (j < 4) ? a0[i][j] : a1[i][j - 4];
                float z = 0.5f * (av + h2f(bv[j][i]));
                bool dg = (i0 + R + i) == (j0 + C + j);
                if (dg) z += 1.0f;
                float s = fast_sigmoid(z);
                if (dg) s += 1.0f;
                u16 h = f2h(s);
                o[j] = h;
                mir[j][i] = h;
                rsum[i] += s;
                csum[j] += s;
            }
            *(u16x8*)(AH + (size_t)(i0 + R + i) * NN + j0 + C) = o;
        }
        if (!diag) {
            #pragma unroll
            for (int j = 0; j < 8; ++j) {
                int r = C + j;
                int pos = (rb >> 1) ^ (cb & 7);
                *(u16x4*)&hB[r * LW + pos * 8 + (rb & 1) * 4] = mir[j];
            }
        }
    }

    #pragma unroll
    for (int m = 1; m <= 8; m <<= 1) {
        #pragma unroll
        for (int i = 0; i < 4; ++i) rsum[i] += __shfl_xor(rsum[i], m);
    }
    if (cb == 0) {
        f32x4 rv = {rsum[0], rsum[1], rsum[2], rsum[3]};
        *(f32x4*)&psum[(size_t)bj * NN + i0 + R] = rv;
    }

    if (!diag) {
        #pragma unroll
        for (int j = 0; j < 8; ++j) {
            csum[j] += __shfl_xor(csum[j], 16);
            csum[j] += __shfl_xor(csum[j], 32);
        }
        const int w = t >> 6;
        if ((t & 48) == 0) {
            #pragma unroll
            for (int j = 0; j < 8; ++j) cs[w][C + j] = csum[j];
        }
    }
    __syncthreads();

    if (!diag) {
        const int r2 = t >> 4, m = t & 15;
        #pragma unroll
        for (int p = 0; p < 4; ++p) {
            int rr = r2 + p * 32;
            int pos = m ^ ((rr >> 3) & 7);
            *(u16x8*)(AH + (size_t)(j0 + rr) * NN + i0 + m * 8) =
                *(const u16x8*)&hB[rr * LW + pos * 8];
        }
        if (t < 128) {
            float s = 0.f;
            #pragma unroll
            for (int k = 0; k < 8; ++k) s += cs[k][t];
            psum[(size_t)bi * NN + j0 + t] = s;   // unique writer
        }
    }
}

// ---------------------------------------------------------------------------
// k_xw1: psum reduce -> rowsum, then scaled x@W1 -> XW1T.
// ---------------------------------------------------------------------------
__global__ __launch_bounds__(256) void k_xw1(const float* __restrict__ x,
                                             const float* __restrict__ W1,
                                             const float* __restrict__ psum,
                                             float* __restrict__ rowsum,
                                             u16* __restrict__ XW1T) {
    const int t = threadIdx.x;
    __shared__ float xs[32 * 129];
    __shared__ float rs_s[32];
    const int i0 = blockIdx.x * 32;
    if (t < 32) {
        float rs = 0.f;
        #pragma unroll 8
        for (int v = 0; v < 64; ++v) rs += psum[(size_t)v * NN + i0 + t];
        rs_s[t] = rs;
        rowsum[i0 + t] = rs;                  // publish for epi1/epi2
    }
    #pragma unroll
    for (int p = 0; p < 4; ++p) {
        int idx = p * 256 + t;
        int r = idx >> 5, c4 = idx & 31;
        f32x4 v = __builtin_nontemporal_load(
            (const f32x4*)(x + (size_t)(i0 + r) * INC + c4 * 4));
        int o = r * 129 + c4 * 4;
        xs[o] = v[0]; xs[o + 1] = v[1]; xs[o + 2] = v[2]; xs[o + 3] = v[3];
    }
    __syncthreads();
    const int i = t & 31, g = t >> 5;
    const float di = 1.0f / sqrtf(rs_s[i]);
    #pragma unroll
    for (int p = 0; p < 2; ++p) {
        const int cbase = g * 32 + p * 16;
        float acc[16];
        #pragma unroll
        for (int cc = 0; cc < 16; ++cc) acc[cc] = 0.f;
        for (int k = 0; k < 128; ++k) {
            float xv = xs[i * 129 + k];
            const float4* wr4 = reinterpret_cast<const float4*>(W1 + k * HIDC + cbase);
            float4 w0 = wr4[0], w1 = wr4[1], w2 = wr4[2], w3 = wr4[3];
            acc[0]  = fmaf(xv, w0.x, acc[0]);  acc[1]  = fmaf(xv, w0.y, acc[1]);
            acc[2]  = fmaf(xv, w0.z, acc[2]);  acc[3]  = fmaf(xv, w0.w, acc[3]);
            acc[4]  = fmaf(xv, w1.x, acc[4]);  acc[5]  = fmaf(xv, w1.y, acc[5]);
            acc[6]  = fmaf(xv, w1.z, acc[6]);  acc[7]  = fmaf(xv, w1.w, acc[7]);
            acc[8]  = fmaf(xv, w2.x, acc[8]);  acc[9]  = fmaf(xv, w2.y, acc[9]);
            acc[10] = fmaf(xv, w2.z, acc[10]); acc[11] = fmaf(xv, w2.w, acc[11]);
            acc[12] = fmaf(xv, w3.x, acc[12]); acc[13] = fmaf(xv, w3.y, acc[13]);
            acc[14] = fmaf(xv, w3.z, acc[14]); acc[15] = fmaf(xv, w3.w, acc[15]);
        }
        #pragma unroll
        for (int cc = 0; cc < 16; ++cc)
            XW1T[(size_t)(cbase + cc) * NN + i0 + i] = f2h(di * acc[cc]);
    }
}

// ---------------------------------------------------------------------------
// 8-phase MFMA GEMM, BM=256, BK=64, 8 waves. Fragment-native C-write
// (regular stores — R8's NT variant was neutral-negative, reverted).
// ---------------------------------------------------------------------------
#define PH_MID() do { __builtin_amdgcn_s_barrier();                             \
    asm volatile("s_waitcnt lgkmcnt(0)" ::: "memory");                          \
    __builtin_amdgcn_sched_barrier(0);                                          \
    __builtin_amdgcn_s_setprio(1); } while (0)

#define PH_NW() do { __builtin_amdgcn_s_setprio(0);                             \
    __builtin_amdgcn_s_barrier(); } while (0)

#define PH_W() do { __builtin_amdgcn_s_setprio(0);                              \
    if constexpr (BN == 256) { asm volatile("s_waitcnt vmcnt(6)" ::: "memory"); } \
    else                     { asm volatile("s_waitcnt vmcnt(4)" ::: "memory"); } \
    __builtin_amdgcn_s_barrier(); } while (0)

#define PH_W0() do { __builtin_amdgcn_s_setprio(0);                             \
    asm volatile("s_waitcnt vmcnt(0)" ::: "memory");                            \
    __builtin_amdgcn_s_barrier(); } while (0)

template <int BN>
__global__ __launch_bounds__(512, 2) void k_gemm8(const u16* __restrict__ A,
                                                  const u16* __restrict__ BT,
                                                  u16* __restrict__ partial) {
    constexpr int NI = BN / 128;
    constexpr int NQB = BN / 64;
    constexpr int BUFB = BN * 128;
    constexpr int KCH = NN / KSPLIT;          // 1024
    constexpr int NT = KCH / 64;              // 16
    constexpr int ITER = NT / 2;              // 8 (last peeled)
    __shared__ __align__(16) char lds[65536 + 2 * BUFB];

    const int t = threadIdx.x;
    const int l = t & 63, w = t >> 6;
    const int wr = w >> 2, wc = w & 3;
    const int g2 = (blockIdx.x & 7) * 32 + (blockIdx.x >> 3);
    const int m0 = (g2 & 31) * 256;
    const int kc = g2 >> 5;
    const int kbase = kc * KCH;

    const int D16 = t * 16;
    const int Ds = D16 ^ (((D16 >> 7) & 7) << 4);
    const int rS = Ds >> 7, cS = (Ds & 127) >> 1;

    f32x4 acc[8][NI * 2];
    #pragma unroll
    for (int i = 0; i < 8; ++i)
        #pragma unroll
        for (int j = 0; j < NI * 2; ++j) acc[i][j] = {0.f, 0.f, 0.f, 0.f};

    f16x8 a[4][2];
    f16x8 bf[2][NI][2];

    auto stageA = [&](int b, int q, int tile) {
        GLD16(A + (size_t)(m0 + q * 64 + rS) * NN + kbase + tile * 64 + cS,
              &lds[b * 32768 + q * 8192 + D16]);
    };
    auto stageB = [&](int b, int q, int tile) {
        GLD16(BT + (size_t)(q * 64 + rS) * NN + kbase + tile * 64 + cS,
              &lds[65536 + b * BUFB + q * 8192 + D16]);
    };
    auto readA = [&](int b, int mh) {
        #pragma unroll
        for (int mi = 0; mi < 4; ++mi)
            #pragma unroll
            for (int s = 0; s < 2; ++s) {
                int r = wr * 128 + mh * 64 + mi * 16 + (l & 15);
                a[mi][s] = *(const f16x8*)&lds[b * 32768 + r * 128 +
                    ((s * 64 + ((l >> 4) * 16)) ^ ((r & 7) << 4))];
            }
    };
    auto readB = [&](int b, int nh) {
        #pragma unroll
        for (int ni = 0; ni < NI; ++ni)
            #pragma unroll
            for (int s = 0; s < 2; ++s) {
                int r = wc * (BN / 4) + nh * (NI * 16) + ni * 16 + (l & 15);
                bf[nh][ni][s] = *(const f16x8*)&lds[65536 + b * BUFB + r * 128 +
                    ((s * 64 + ((l >> 4) * 16)) ^ ((r & 7) << 4))];
            }
    };
    auto mfmaq = [&](int mh, int nh) {
        #pragma unroll
        for (int s = 0; s < 2; ++s)
            #pragma unroll
            for (int mi = 0; mi < 4; ++mi)
                #pragma unroll
                for (int ni = 0; ni < NI; ++ni)
                    acc[mh * 4 + mi][nh * NI + ni] =
                        __builtin_amdgcn_mfma_f32_16x16x32_f16(a[mi][s], bf[nh][ni][s],
                            acc[mh * 4 + mi][nh * NI + ni], 0, 0, 0);
    };

    #pragma unroll
    for (int q = 0; q < NQB; ++q) stageB(0, q, 0);
    #pragma unroll
    for (int q = 0; q < 4; ++q) stageA(0, q, 0);
    #pragma unroll
    for (int q = 0; q < NQB; ++q) stageB(1, q, 1);
    stageA(1, 0, 1); stageA(1, 1, 1);
    if constexpr (BN == 256) { asm volatile("s_waitcnt vmcnt(6)" ::: "memory"); }
    else                     { asm volatile("s_waitcnt vmcnt(4)" ::: "memory"); }
    __builtin_amdgcn_s_barrier();

    for (int it = 0; it < ITER - 1; ++it) {
        const int TP = 2 * it + 1, TE = 2 * it + 2, TO = 2 * it + 3;
        readA(0, 0); readB(0, 0); stageA(1, 2, TP); stageA(1, 3, TP);
        PH_MID(); mfmaq(0, 0); PH_NW();
        readB(0, 1);
        PH_MID(); mfmaq(0, 1); PH_NW();
        readA(0, 1); stageB(0, 0, TE); stageB(0, 1, TE);
        PH_MID(); mfmaq(1, 0); PH_NW();
        if constexpr (BN == 256) { stageB(0, 2, TE); stageB(0, 3, TE); }
        stageA(0, 0, TE); stageA(0, 1, TE);
        PH_MID(); mfmaq(1, 1); PH_W();
        readA(1, 0); readB(1, 0); stageA(0, 2, TE); stageA(0, 3, TE);
        PH_MID(); mfmaq(0, 0); PH_NW();
        readB(1, 1);
        PH_MID(); mfmaq(0, 1); PH_NW();
        readA(1, 1); stageB(1, 0, TO); stageB(1, 1, TO);
        PH_MID(); mfmaq(1, 0); PH_NW();
        if constexpr (BN == 256) { stageB(1, 2, TO); stageB(1, 3, TO); }
        stageA(1, 0, TO); stageA(1, 1, TO);
        PH_MID(); mfmaq(1, 1); PH_W();
    }
    readA(0, 0); readB(0, 0); stageA(1, 2, NT - 1); stageA(1, 3, NT - 1);
    PH_MID(); mfmaq(0, 0); PH_NW();
    readB(0, 1);
    PH_MID(); mfmaq(0, 1); PH_NW();
    readA(0, 1);
    PH_MID(); mfmaq(1, 0); PH_NW();
    PH_MID(); mfmaq(1, 1); PH_W0();
    readA(1, 0); readB(1, 0);
    PH_MID(); mfmaq(0, 0); PH_NW();
    readB(1, 1);
    PH_MID(); mfmaq(0, 1); PH_NW();
    readA(1, 1);
    PH_MID(); mfmaq(1, 0); PH_NW();
    PH_MID(); mfmaq(1, 1);
    __builtin_amdgcn_s_setprio(0);

    // ---- fragment-native C-write: 8B/lane, 512B contiguous per fragment
    u16* pout = partial + (size_t)kc * NN * BN + (size_t)(g2 & 31) * (256 * BN);
    #pragma unroll
    for (int mh = 0; mh < 2; ++mh)
        #pragma unroll
        for (int mi = 0; mi < 4; ++mi)
            #pragma unroll
            for (int nh = 0; nh < 2; ++nh)
                #pragma unroll
                for (int ni = 0; ni < NI; ++ni) {
                    int f = (((w * 2 + mh) * 4 + mi) * 2 + nh) * NI + ni;
                    u16x4 v;
                    #pragma unroll
                    for (int j = 0; j < 4; ++j)
                        v[j] = f2h(acc[mh * 4 + mi][nh * NI + ni][j]);
                    *(u16x4*)(pout + ((size_t)f * 64 + l) * 4) = v;
                }
}

// ---------------------------------------------------------------------------
// Fused epi1 + h@W2, fragment-native partial reads.
// ---------------------------------------------------------------------------
__global__ __launch_bounds__(512) void k_epi1hw2m(const u16* __restrict__ partial,
                                                  const float* __restrict__ rowsum,
                                                  const float* __restrict__ b1,
                                                  const u16* __restrict__ W2T,
                                                  u16* __restrict__ HW2T) {
    __shared__ __align__(16) char lds[81920];
    const int t = threadIdx.x;
    const int l = t & 63, w = t >> 6;
    const int i0 = blockIdx.x * 32;

    #pragma unroll
    for (int p = 0; p < 8; ++p) {
        int D = (p * 512 + t) * 16;
        int row = D >> 9;
        int col = (D & 511) ^ ((row & 7) << 4);
        GLD16(W2T + (size_t)row * HIDC + (col >> 1), &lds[D]);
    }

    // ---- decode fragment coords: rows i0+rq*4..+3, cols c..c+3
    {
        const int rq = w;                     // row-quad 0..7
        const int c = l * 4;                  // col 0..252
        const int cl = c & 15, ni = (c >> 4) & 1, nh = (c >> 5) & 1, wcq = c >> 6;
        const int lr0 = i0 & 255;
        const int wrq = lr0 >> 7, mhq = (lr0 >> 6) & 1;
        const int mi = ((lr0 >> 4) & 3) + (rq >> 2);
        const int lgrp = rq & 3;
        const int mb = i0 >> 8;
        const int f = ((((wrq * 4 + wcq) * 2 + mhq) * 4 + mi) * 2 + nh) * 2 + ni;
        const size_t boff = (size_t)mb * 65536 + ((size_t)f * 64 + lgrp * 16 + cl) * 4;
        float s[16];
        #pragma unroll
        for (int e = 0; e < 16; ++e) s[e] = 0.f;
        #pragma unroll
        for (int kc = 0; kc < KSPLIT; ++kc) {
            const u16* src = partial + (size_t)kc * NN * HIDC + boff;
            u16x8 p0 = __builtin_nontemporal_load((const u16x8*)src);
            u16x8 p1 = __builtin_nontemporal_load((const u16x8*)(src + 8));
            #pragma unroll
            for (int e = 0; e < 8; ++e) { s[e] += h2f(p0[e]); s[8 + e] += h2f(p1[e]); }
        }
        float di[4];
        #pragma unroll
        for (int j = 0; j < 4; ++j) di[j] = 1.0f / sqrtf(rowsum[i0 + rq * 4 + j]);
        f32x4 b1v = *(const f32x4*)(b1 + c);
        #pragma unroll
        for (int k = 0; k < 4; ++k)
            #pragma unroll
            for (int j = 0; j < 4; ++j) {
                float hv = di[j] * fmaxf(fmaf(di[j], s[k * 4 + j], b1v[k]), 0.f);
                int il = rq * 4 + j;
                *(u16*)&lds[65536 + il * 512 + ((2 * (c + k)) ^ ((il & 7) << 4))] = f2h(hv);
            }
    }
    asm volatile("s_waitcnt vmcnt(0)" ::: "memory");
    __syncthreads();

    const int wm = w >> 1, wn = w & 1;        // wm 0..3 (c-quad), wn 0..1 (i-half)
    f32x4 acc[2];
    acc[0] = {0.f, 0.f, 0.f, 0.f}; acc[1] = {0.f, 0.f, 0.f, 0.f};
    for (int kt = 0; kt < 8; ++kt) {
        f16x8 av[2], bv;
        const int cb2 = kt * 64 + (l >> 4) * 16;
        #pragma unroll
        for (int mi = 0; mi < 2; ++mi) {
            int r = wm * 32 + mi * 16 + (l & 15);
            av[mi] = *(const f16x8*)&lds[r * 512 + (cb2 ^ ((r & 7) << 4))];
        }
        {
            int ri = wn * 16 + (l & 15);
            bv = *(const f16x8*)&lds[65536 + ri * 512 + (cb2 ^ ((ri & 7) << 4))];
        }
        #pragma unroll
        for (int mi = 0; mi < 2; ++mi)
            acc[mi] = __builtin_amdgcn_mfma_f32_16x16x32_f16(av[mi], bv, acc[mi], 0, 0, 0);
    }
    #pragma unroll
    for (int mi = 0; mi < 2; ++mi)
        #pragma unroll
        for (int j = 0; j < 4; ++j) {
            int c = wm * 32 + mi * 16 + (l >> 4) * 4 + j;
            int ic = wn * 16 + (l & 15);
            HW2T[(size_t)c * NN + i0 + ic] = f2h(acc[mi][j]);
        }
}

// ---------------------------------------------------------------------------
// Final epilogue, fragment-native partial reads (BN=128, NI=1).
// ---------------------------------------------------------------------------
__global__ __launch_bounds__(256) void k_epi2(const u16* __restrict__ partial,
                                              const float* __restrict__ rowsum,
                                              const float* __restrict__ b2,
                                              float* __restrict__ out) {
    const int idx = blockIdx.x * 256 + threadIdx.x;   // 65536 = NN*OUTC/16
    const int rq = idx >> 5;              // row-quad 0..2047
    const int c4g = idx & 31;
    const int c = c4g * 4;
    const int cl = c & 15, nh = (c >> 4) & 1, wc = c >> 5;
    const int mb = rq >> 6;
    const int lr4 = rq & 63;              // row-quad within 256-row panel
    const int wr = lr4 >> 5, mh = (lr4 >> 4) & 1, mi = (lr4 >> 2) & 3, lgrp = lr4 & 3;
    const int f = (((wr * 4 + wc) * 2 + mh) * 4 + mi) * 2 + nh;
    const size_t boff = (size_t)mb * 32768 + ((size_t)f * 64 + lgrp * 16 + cl) * 4;
    float s[16];
    #pragma unroll
    for (int e = 0; e < 16; ++e) s[e] = 0.f;
    #pragma unroll
    for (int kc = 0; kc < KSPLIT; ++kc) {
        const u16* src = partial + (size_t)kc * NN * OUTC + boff;
        u16x8 p0 = __builtin_nontemporal_load((const u16x8*)src);
        u16x8 p1 = __builtin_nontemporal_load((const u16x8*)(src + 8));
        #pragma unroll
        for (int e = 0; e < 8; ++e) { s[e] += h2f(p0[e]); s[8 + e] += h2f(p1[e]); }
    }
    const int i_base = rq * 4;
    f32x4 b2v = *(const f32x4*)(b2 + c);
    #pragma unroll
    for (int j = 0; j < 4; ++j) {
        const float di = 1.0f / sqrtf(rowsum[i_base + j]);
        float4 o = make_float4(fmaf(di, s[0 * 4 + j], b2v[0]),
                               fmaf(di, s[1 * 4 + j], b2v[1]),
                               fmaf(di, s[2 * 4 + j], b2v[2]),
                               fmaf(di, s[3 * 4 + j], b2v[3]));
        *reinterpret_cast<float4*>(out + (size_t)(i_base + j) * OUTC + c) = o;
    }
}

// ---------------------------------------------------------------------------
extern "C" void kernel_launch(void* const* d_in, const int* in_sizes, int n_in,
                              void* d_out, int out_size, void* d_ws, size_t ws_size,
                              hipStream_t stream) {
    const float* x  = (const float*)d_in[0];
    const float* P  = (const float*)d_in[1];
    const float* W1 = (const float*)d_in[2];
    const float* b1 = (const float*)d_in[3];
    const float* W2 = (const float*)d_in[4];
    const float* b2 = (const float*)d_in[5];
    float* out = (float*)d_out;
    char* ws = (char*)d_ws;

    u16*   AH      = (u16*)(ws);                    // 134,217,728 B
    u16*   XW1T    = (u16*)(ws + 134217728ull);     // 4 MB
    u16*   W2T     = (u16*)(ws + 138412032ull);     // 64 KB
    u16*   HW2T    = (u16*)(ws + 138477568ull);     // 2 MB
    float* rowsum  = (float*)(ws + 140574720ull);   // 32 KB
    u16*   partial = (u16*)(ws + 140607488ull);     // 33.5 MB
    float* psum    = (float*)(ws + 174161920ull);   // 2 MB (64 x 8192 fp32)

    k_adj<<<2081, 512, 0, stream>>>(P, AH, psum, W2, W2T);
    k_xw1<<<256, 256, 0, stream>>>(x, W1, psum, rowsum, XW1T);
    k_gemm8<HIDC><<<256, 512, 0, stream>>>(AH, XW1T, partial);
    k_epi1hw2m<<<256, 512, 0, stream>>>(partial, rowsum, b1, W2T, HW2T);
    k_gemm8<OUTC><<<256, 512, 0, stream>>>(AH, HW2T, partial);
    k_epi2<<<256, 256, 0, stream>>>(partial, rowsum, b2, out);
}